// Round 1
// baseline (713.160 us; speedup 1.0000x reference)
//
#include <hip/hip_runtime.h>

#define N_NODES 8192
#define HDIM    512
#define NEDGE   262144

typedef __attribute__((ext_vector_type(8))) short bf16x8;
typedef __attribute__((ext_vector_type(4))) float f32x4;

__device__ inline unsigned short f2bf(float f) {
  unsigned u = __float_as_uint(f);
  unsigned r = (u + 0x7FFFu + ((u >> 16) & 1u)) >> 16;
  return (unsigned short)r;
}

// ---------------- CSR build ----------------
__global__ void zero_kernel(int* __restrict__ p) {
  p[blockIdx.x * 256 + threadIdx.x] = 0;
}

__global__ void hist_kernel(const int* __restrict__ rows, int* __restrict__ counts) {
  int e = blockIdx.x * 256 + threadIdx.x;
  atomicAdd(&counts[rows[e]], 1);
}

__global__ __launch_bounds__(1024) void scan_kernel(const int* __restrict__ counts,
                                                    int* __restrict__ offs,
                                                    int* __restrict__ cursor) {
  __shared__ int s[1024];
  int tid = threadIdx.x;
  int local[8];
  int sum = 0;
#pragma unroll
  for (int i = 0; i < 8; ++i) { local[i] = counts[tid * 8 + i]; sum += local[i]; }
  s[tid] = sum;
  __syncthreads();
  for (int d = 1; d < 1024; d <<= 1) {
    int v = (tid >= d) ? s[tid - d] : 0;
    __syncthreads();
    s[tid] += v;
    __syncthreads();
  }
  int base = (tid > 0) ? s[tid - 1] : 0;
#pragma unroll
  for (int i = 0; i < 8; ++i) {
    offs[tid * 8 + i] = base;
    cursor[tid * 8 + i] = base;
    base += local[i];
  }
  if (tid == 1023) offs[8192] = base;
}

__global__ void scatter_kernel(const int* __restrict__ rows, int* cursor,
                               int* __restrict__ eidx) {
  int e = blockIdx.x * 256 + threadIdx.x;
  int slot = atomicAdd(&cursor[rows[e]], 1);
  eidx[slot] = e;
}

// ---------------- SpMM (CSR, wave per row) ----------------
__global__ __launch_bounds__(256) void spmm_kernel(const int* __restrict__ offs,
                                                   const int* __restrict__ eidx,
                                                   const int* __restrict__ cols,
                                                   const float* __restrict__ vals,
                                                   const float* __restrict__ X,
                                                   float* __restrict__ Y) {
  int row = blockIdx.x * 4 + (threadIdx.x >> 6);
  int lane = threadIdx.x & 63;
  int h0 = lane * 8;
  float4 acc0 = make_float4(0.f, 0.f, 0.f, 0.f);
  float4 acc1 = make_float4(0.f, 0.f, 0.f, 0.f);
  int e0 = offs[row], e1 = offs[row + 1];
  for (int p = e0; p < e1; ++p) {
    int e = eidx[p];
    float v = vals[e];
    int c = cols[e];
    const float4* xp = reinterpret_cast<const float4*>(X + (size_t)c * HDIM + h0);
    float4 a = xp[0], b = xp[1];
    acc0.x = fmaf(v, a.x, acc0.x); acc0.y = fmaf(v, a.y, acc0.y);
    acc0.z = fmaf(v, a.z, acc0.z); acc0.w = fmaf(v, a.w, acc0.w);
    acc1.x = fmaf(v, b.x, acc1.x); acc1.y = fmaf(v, b.y, acc1.y);
    acc1.z = fmaf(v, b.z, acc1.z); acc1.w = fmaf(v, b.w, acc1.w);
  }
  float4* yp = reinterpret_cast<float4*>(Y + (size_t)row * HDIM + h0);
  yp[0] = acc0;
  yp[1] = acc1;
}

// ---------------- elementwise multiply ----------------
__global__ void ewmul_kernel(const float* __restrict__ a, const float* __restrict__ b,
                             float* __restrict__ o) {
  size_t i = ((size_t)blockIdx.x * 256 + threadIdx.x) * 4;
  float4 x = *reinterpret_cast<const float4*>(a + i);
  float4 y = *reinterpret_cast<const float4*>(b + i);
  float4 z = make_float4(x.x * y.x, x.y * y.y, x.z * y.z, x.w * y.w);
  *reinterpret_cast<float4*>(o + i) = z;
}

// ---------------- f32 -> bf16 cast into strided dst ----------------
__global__ void cast_kernel(const float* __restrict__ src, short* __restrict__ dst,
                            int ld, int coloff) {
  int t = blockIdx.x * 256 + threadIdx.x;
  int row = t >> 6;
  int c0 = (t & 63) * 8;
  const float4* p = reinterpret_cast<const float4*>(src + (size_t)row * HDIM + c0);
  float4 a = p[0], b = p[1];
  bf16x8 o;
  o[0] = (short)f2bf(a.x); o[1] = (short)f2bf(a.y);
  o[2] = (short)f2bf(a.z); o[3] = (short)f2bf(a.w);
  o[4] = (short)f2bf(b.x); o[5] = (short)f2bf(b.y);
  o[6] = (short)f2bf(b.z); o[7] = (short)f2bf(b.w);
  *reinterpret_cast<bf16x8*>(dst + (size_t)row * ld + coloff + c0) = o;
}

__global__ void bias_kernel(const float* __restrict__ b1, const float* __restrict__ b2,
                            float* __restrict__ b12) {
  int j = blockIdx.x * 256 + threadIdx.x;
  if (j < HDIM) b12[j] = b1[j] + b2[j];
}

// ---------------- row L2 normalize + bf16 copy ----------------
__global__ __launch_bounds__(256) void rownorm_kernel(const float* __restrict__ X,
                                                      float* __restrict__ outf,
                                                      short* __restrict__ outb) {
  int row = blockIdx.x * 4 + (threadIdx.x >> 6);
  int lane = threadIdx.x & 63;
  int h0 = lane * 8;
  const float4* p = reinterpret_cast<const float4*>(X + (size_t)row * HDIM + h0);
  float4 a = p[0], b = p[1];
  float s = a.x * a.x + a.y * a.y + a.z * a.z + a.w * a.w +
            b.x * b.x + b.y * b.y + b.z * b.z + b.w * b.w;
#pragma unroll
  for (int off = 1; off < 64; off <<= 1) s += __shfl_xor(s, off, 64);
  float inv = 1.f / fmaxf(sqrtf(s), 1e-12f);
  a.x *= inv; a.y *= inv; a.z *= inv; a.w *= inv;
  b.x *= inv; b.y *= inv; b.z *= inv; b.w *= inv;
  float4* q = reinterpret_cast<float4*>(outf + (size_t)row * HDIM + h0);
  q[0] = a; q[1] = b;
  bf16x8 o;
  o[0] = (short)f2bf(a.x); o[1] = (short)f2bf(a.y);
  o[2] = (short)f2bf(a.z); o[3] = (short)f2bf(a.w);
  o[4] = (short)f2bf(b.x); o[5] = (short)f2bf(b.y);
  o[6] = (short)f2bf(b.z); o[7] = (short)f2bf(b.w);
  *reinterpret_cast<bf16x8*>(outb + (size_t)row * HDIM + h0) = o;
}

// ---------------- bf16 MFMA GEMM: C[M,N] = A[M,K] * B[N,K]^T ----------------
// MODE 0: out0 = C + bias (pre), out1 = elu(pre)
// MODE 1: out0 = resid + 0.4*elu(C + bias)
// MODE 2: out0 = relu(C)
template <int MODE>
__global__ __launch_bounds__(256) void gemm_kernel(const short* __restrict__ A,
                                                   const short* __restrict__ B,
                                                   int M, int N, int K,
                                                   const float* __restrict__ bias,
                                                   const float* __restrict__ resid,
                                                   float* __restrict__ out0,
                                                   float* __restrict__ out1) {
  int lane = threadIdx.x & 63;
  int wave = threadIdx.x >> 6;
  int bm = blockIdx.y * 128 + (wave >> 1) * 64;
  int bn = blockIdx.x * 128 + (wave & 1) * 64;
  int rlo = lane & 15;
  int kseg = (lane >> 4) * 8;

  const short* pa[4];
  const short* pb[4];
#pragma unroll
  for (int m = 0; m < 4; ++m) pa[m] = A + (size_t)(bm + m * 16 + rlo) * K + kseg;
#pragma unroll
  for (int n = 0; n < 4; ++n) pb[n] = B + (size_t)(bn + n * 16 + rlo) * K + kseg;

  f32x4 zero = {0.f, 0.f, 0.f, 0.f};
  f32x4 acc[4][4];
#pragma unroll
  for (int m = 0; m < 4; ++m)
#pragma unroll
    for (int n = 0; n < 4; ++n) acc[m][n] = zero;

  for (int kk = 0; kk < K; kk += 32) {
    bf16x8 av[4], bv[4];
#pragma unroll
    for (int m = 0; m < 4; ++m) av[m] = *reinterpret_cast<const bf16x8*>(pa[m] + kk);
#pragma unroll
    for (int n = 0; n < 4; ++n) bv[n] = *reinterpret_cast<const bf16x8*>(pb[n] + kk);
#pragma unroll
    for (int m = 0; m < 4; ++m)
#pragma unroll
      for (int n = 0; n < 4; ++n)
        acc[m][n] = __builtin_amdgcn_mfma_f32_16x16x32_bf16(av[m], bv[n], acc[m][n], 0, 0, 0);
  }

  int crow = (lane >> 4) * 4;
  int ccol = lane & 15;
#pragma unroll
  for (int n = 0; n < 4; ++n) {
    int c = bn + n * 16 + ccol;
    float bc = (MODE == 2) ? 0.f : bias[c];
#pragma unroll
    for (int m = 0; m < 4; ++m) {
#pragma unroll
      for (int v = 0; v < 4; ++v) {
        int r = bm + m * 16 + crow + v;
        size_t idx = (size_t)r * N + c;
        float val = acc[m][n][v];
        if (MODE == 0) {
          float pvl = val + bc;
          out0[idx] = pvl;
          out1[idx] = pvl > 0.f ? pvl : expm1f(pvl);
        } else if (MODE == 1) {
          float pvl = val + bc;
          out0[idx] = resid[idx] + 0.4f * (pvl > 0.f ? pvl : expm1f(pvl));
        } else {
          out0[idx] = val > 0.f ? val : 0.f;
        }
      }
    }
  }
}

extern "C" void kernel_launch(void* const* d_in, const int* in_sizes, int n_in,
                              void* d_out, int out_size, void* d_ws, size_t ws_size,
                              hipStream_t stream) {
  const float* x  = (const float*)d_in[0];
  const int* rows = (const int*)d_in[1];
  const int* cols = (const int*)d_in[2];
  const float* vals = (const float*)d_in[3];
  const float* W1 = (const float*)d_in[4];
  const float* b1 = (const float*)d_in[5];
  const float* W2 = (const float*)d_in[6];
  const float* b2 = (const float*)d_in[7];

  float* out_adj = (float*)d_out;
  float* out_hid = out_adj + (size_t)N_NODES * N_NODES;

  char* w = (char*)d_ws;
  size_t off = 0;
  auto alloc = [&](size_t bytes) -> void* {
    void* p = w + off;
    off += (bytes + 255) & ~(size_t)255;
    return p;
  };
  int* counts = (int*)alloc(8192 * sizeof(int));
  int* offs   = (int*)alloc(8193 * sizeof(int));
  int* cursor = (int*)alloc(8192 * sizeof(int));
  int* eidx   = (int*)alloc((size_t)NEDGE * sizeof(int));
  float* b12  = (float*)alloc(HDIM * sizeof(float));
  float* Ax   = (float*)alloc((size_t)N_NODES * HDIM * sizeof(float));
  float* T    = (float*)alloc((size_t)N_NODES * HDIM * sizeof(float));
  float* Axx  = (float*)alloc((size_t)N_NODES * HDIM * sizeof(float));
  float* pre1 = (float*)alloc((size_t)N_NODES * HDIM * sizeof(float));
  short* Abuf = (short*)alloc((size_t)N_NODES * 1024 * sizeof(short));
  short* Bbuf = (short*)alloc((size_t)512 * 1024 * sizeof(short));
  short* Hbuf = (short*)alloc((size_t)N_NODES * HDIM * sizeof(short));

  // CSR build
  zero_kernel<<<32, 256, 0, stream>>>(counts);
  hist_kernel<<<NEDGE / 256, 256, 0, stream>>>(rows, counts);
  scan_kernel<<<1, 1024, 0, stream>>>(counts, offs, cursor);
  scatter_kernel<<<NEDGE / 256, 256, 0, stream>>>(rows, cursor, eidx);

  // weights / bias prep (tiny)
  bias_kernel<<<2, 256, 0, stream>>>(b1, b2, b12);
  cast_kernel<<<(512 * 64) / 256, 256, 0, stream>>>(W1, Bbuf, 1024, 0);
  cast_kernel<<<(512 * 64) / 256, 256, 0, stream>>>(W2, Bbuf, 1024, 512);

  // ---- layer 1 ----
  spmm_kernel<<<2048, 256, 0, stream>>>(offs, eidx, cols, vals, x, Ax);
  ewmul_kernel<<<4096, 256, 0, stream>>>(Ax, x, T);
  cast_kernel<<<2048, 256, 0, stream>>>(Ax, Abuf, 1024, 0);
  spmm_kernel<<<2048, 256, 0, stream>>>(offs, eidx, cols, vals, T, Axx);
  cast_kernel<<<2048, 256, 0, stream>>>(Axx, Abuf, 1024, 512);
  // pre1 = [Ax|Axx] @ [W1|W2]^T + b12 ; x1 = elu(pre1) -> T
  gemm_kernel<0><<<dim3(4, 64), 256, 0, stream>>>(Abuf, Bbuf, N_NODES, HDIM, 1024,
                                                  b12, nullptr, pre1, T);

  // ---- layer 2 ----
  spmm_kernel<<<2048, 256, 0, stream>>>(offs, eidx, cols, vals, T, Ax);
  ewmul_kernel<<<4096, 256, 0, stream>>>(Ax, T, Axx);
  spmm_kernel<<<2048, 256, 0, stream>>>(offs, eidx, cols, vals, Axx, T);
  cast_kernel<<<2048, 256, 0, stream>>>(Ax, Abuf, 1024, 0);
  cast_kernel<<<2048, 256, 0, stream>>>(T, Abuf, 1024, 512);
  // x2 = pre1 + 0.4*elu([Ax2|Axx2] @ [W1|W2]^T + b12) -> Axx
  gemm_kernel<1><<<dim3(4, 64), 256, 0, stream>>>(Abuf, Bbuf, N_NODES, HDIM, 1024,
                                                  b12, pre1, Axx, nullptr);

  // ---- decoder ----
  rownorm_kernel<<<2048, 256, 0, stream>>>(Axx, out_hid, Hbuf);
  gemm_kernel<2><<<dim3(64, 64), 256, 0, stream>>>(Hbuf, Hbuf, N_NODES, N_NODES, HDIM,
                                                   nullptr, nullptr, out_adj, nullptr);
}

// Round 2
// 386.104 us; speedup vs baseline: 1.8471x; 1.8471x over previous
//
#include <hip/hip_runtime.h>

#define N_NODES 8192
#define HDIM    512
#define NEDGE   262144

typedef __attribute__((ext_vector_type(8))) short bf16x8;
typedef __attribute__((ext_vector_type(4))) float f32x4;

__device__ inline unsigned short f2bf(float f) {
  unsigned u = __float_as_uint(f);
  unsigned r = (u + 0x7FFFu + ((u >> 16) & 1u)) >> 16;
  return (unsigned short)r;
}
__device__ inline float bf2f(short s) {
  return __uint_as_float(((unsigned)(unsigned short)s) << 16);
}

__device__ inline void gload16(const void* g, void* l) {
  __builtin_amdgcn_global_load_lds(
      (const __attribute__((address_space(1))) unsigned*)g,
      (__attribute__((address_space(3))) unsigned*)l, 16, 0, 0);
}

// ---------------- CSR build ----------------
__global__ void zero_kernel(int* __restrict__ p) {
  p[blockIdx.x * 256 + threadIdx.x] = 0;
}

__global__ void hist_kernel(const int* __restrict__ rows, int* __restrict__ counts) {
  int e = blockIdx.x * 256 + threadIdx.x;
  atomicAdd(&counts[rows[e]], 1);
}

__global__ __launch_bounds__(1024) void scan_kernel(const int* __restrict__ counts,
                                                    int* __restrict__ offs,
                                                    int* __restrict__ cursor) {
  __shared__ int s[1024];
  int tid = threadIdx.x;
  int local[8];
  int sum = 0;
#pragma unroll
  for (int i = 0; i < 8; ++i) { local[i] = counts[tid * 8 + i]; sum += local[i]; }
  s[tid] = sum;
  __syncthreads();
  for (int d = 1; d < 1024; d <<= 1) {
    int v = (tid >= d) ? s[tid - d] : 0;
    __syncthreads();
    s[tid] += v;
    __syncthreads();
  }
  int base = (tid > 0) ? s[tid - 1] : 0;
#pragma unroll
  for (int i = 0; i < 8; ++i) {
    offs[tid * 8 + i] = base;
    cursor[tid * 8 + i] = base;
    base += local[i];
  }
  if (tid == 1023) offs[8192] = base;
}

__global__ void scatter_kernel(const int* __restrict__ rows, const int* __restrict__ cols,
                               const float* __restrict__ vals, int* cursor,
                               int* __restrict__ cols_s, float* __restrict__ vals_s) {
  int e = blockIdx.x * 256 + threadIdx.x;
  int slot = atomicAdd(&cursor[rows[e]], 1);
  cols_s[slot] = cols[e];
  vals_s[slot] = vals[e];
}

// ---------------- SpMM (CSR, wave per row, bf16 gather) ----------------
// MODE 0: prod = acc * aux (aux = x, f32)        -> prodb
// MODE 1: prod = acc * elu(aux) (aux = pre1 f32) -> prodb
// MODE 2: no product
template <int MODE>
__global__ __launch_bounds__(256) void spmm_bf(const int* __restrict__ offs,
                                               const int* __restrict__ cols_s,
                                               const float* __restrict__ vals_s,
                                               const short* __restrict__ Xbf,
                                               const float* __restrict__ aux,
                                               short* __restrict__ outb,
                                               short* __restrict__ prodb) {
  int row = blockIdx.x * 4 + (threadIdx.x >> 6);
  int lane = threadIdx.x & 63;
  int h0 = lane * 8;
  float acc[8] = {0.f, 0.f, 0.f, 0.f, 0.f, 0.f, 0.f, 0.f};
  int e0 = offs[row], e1 = offs[row + 1];
  for (int p = e0; p < e1; ++p) {
    float v = vals_s[p];
    int c = cols_s[p];
    bf16x8 xr = *reinterpret_cast<const bf16x8*>(Xbf + (size_t)c * HDIM + h0);
#pragma unroll
    for (int j = 0; j < 8; ++j) acc[j] = fmaf(v, bf2f(xr[j]), acc[j]);
  }
  bf16x8 o;
#pragma unroll
  for (int j = 0; j < 8; ++j) o[j] = (short)f2bf(acc[j]);
  *reinterpret_cast<bf16x8*>(outb + (size_t)row * 1024 + h0) = o;
  if (MODE != 2) {
    const float4* ap = reinterpret_cast<const float4*>(aux + (size_t)row * HDIM + h0);
    float4 a0 = ap[0], a1 = ap[1];
    float xv[8] = {a0.x, a0.y, a0.z, a0.w, a1.x, a1.y, a1.z, a1.w};
    if (MODE == 1) {
#pragma unroll
      for (int j = 0; j < 8; ++j) xv[j] = xv[j] > 0.f ? xv[j] : expm1f(xv[j]);
    }
    bf16x8 t;
#pragma unroll
    for (int j = 0; j < 8; ++j) t[j] = (short)f2bf(acc[j] * xv[j]);
    *reinterpret_cast<bf16x8*>(prodb + (size_t)row * HDIM + h0) = t;
  }
}

// ---------------- f32 -> bf16 cast into strided dst ----------------
__global__ void cast_kernel(const float* __restrict__ src, short* __restrict__ dst,
                            int ld, int coloff) {
  int t = blockIdx.x * 256 + threadIdx.x;
  int row = t >> 6;
  int c0 = (t & 63) * 8;
  const float4* p = reinterpret_cast<const float4*>(src + (size_t)row * HDIM + c0);
  float4 a = p[0], b = p[1];
  bf16x8 o;
  o[0] = (short)f2bf(a.x); o[1] = (short)f2bf(a.y);
  o[2] = (short)f2bf(a.z); o[3] = (short)f2bf(a.w);
  o[4] = (short)f2bf(b.x); o[5] = (short)f2bf(b.y);
  o[6] = (short)f2bf(b.z); o[7] = (short)f2bf(b.w);
  *reinterpret_cast<bf16x8*>(dst + (size_t)row * ld + coloff + c0) = o;
}

__global__ void bias_kernel(const float* __restrict__ b1, const float* __restrict__ b2,
                            float* __restrict__ b12) {
  int j = blockIdx.x * 256 + threadIdx.x;
  if (j < HDIM) b12[j] = b1[j] + b2[j];
}

// ---------------- row L2 normalize + bf16 copy ----------------
__global__ __launch_bounds__(256) void rownorm_kernel(const float* __restrict__ X,
                                                      float* __restrict__ outf,
                                                      short* __restrict__ outb) {
  int row = blockIdx.x * 4 + (threadIdx.x >> 6);
  int lane = threadIdx.x & 63;
  int h0 = lane * 8;
  const float4* p = reinterpret_cast<const float4*>(X + (size_t)row * HDIM + h0);
  float4 a = p[0], b = p[1];
  float s = a.x * a.x + a.y * a.y + a.z * a.z + a.w * a.w +
            b.x * b.x + b.y * b.y + b.z * b.z + b.w * b.w;
#pragma unroll
  for (int off = 1; off < 64; off <<= 1) s += __shfl_xor(s, off, 64);
  float inv = 1.f / fmaxf(sqrtf(s), 1e-12f);
  a.x *= inv; a.y *= inv; a.z *= inv; a.w *= inv;
  b.x *= inv; b.y *= inv; b.z *= inv; b.w *= inv;
  float4* q = reinterpret_cast<float4*>(outf + (size_t)row * HDIM + h0);
  q[0] = a; q[1] = b;
  bf16x8 o;
  o[0] = (short)f2bf(a.x); o[1] = (short)f2bf(a.y);
  o[2] = (short)f2bf(a.z); o[3] = (short)f2bf(a.w);
  o[4] = (short)f2bf(b.x); o[5] = (short)f2bf(b.y);
  o[6] = (short)f2bf(b.z); o[7] = (short)f2bf(b.w);
  *reinterpret_cast<bf16x8*>(outb + (size_t)row * HDIM + h0) = o;
}

// ---------------- LDS-staged bf16 MFMA GEMM: C[M,N] = A[M,K] * B[N,K]^T ----
// 128x128 tile, BK=64, global_load_lds w=16, XOR chunk swizzle both sides.
// MODE 0: out0 = C + bias (pre, f32, ld N); out1bf = bf16(elu(pre))
// MODE 1: out0 = resid + 0.4*elu(C + bias)
// MODE 2: out0 = relu(C)
template <int MODE>
__global__ __launch_bounds__(256) void gemm_lds(const short* __restrict__ A,
                                                const short* __restrict__ B,
                                                int N, int K, int nbn,
                                                const float* __restrict__ bias,
                                                const float* __restrict__ resid,
                                                float* __restrict__ out0,
                                                short* __restrict__ out1bf) {
  __shared__ __align__(16) short la[128 * 64];
  __shared__ __align__(16) short lb[128 * 64];

  // bijective XCD swizzle (gridDim.x % 8 == 0 always here)
  int q = gridDim.x >> 3;
  int id = (blockIdx.x & 7) * q + (blockIdx.x >> 3);
  int bn = (id % nbn) * 128;
  int bm = (id / nbn) * 128;

  int lane = threadIdx.x & 63;
  int wave = threadIdx.x >> 6;

  // staging: segment s = wave*4 + j; lane covers linear byte s*1024 + lane*16
  // row r = s*8 + (lane>>3); physical chunk = lane&7; logical chunk = (lane&7)^(r&7)
  int rsub = lane >> 3;                 // 0..7, == r&7
  int csrc = (lane & 7) ^ rsub;         // logical source chunk (0..7)
  size_t ldkB = (size_t)K * 2;
  const char* gA0 = (const char*)A + (size_t)(bm + wave * 32 + rsub) * ldkB + csrc * 16;
  const char* gB0 = (const char*)B + (size_t)(bn + wave * 32 + rsub) * ldkB + csrc * 16;
  char* lA0 = (char*)la + wave * 4096;
  char* lB0 = (char*)lb + wave * 4096;

  f32x4 zero = {0.f, 0.f, 0.f, 0.f};
  f32x4 acc[4][4];
#pragma unroll
  for (int m = 0; m < 4; ++m)
#pragma unroll
    for (int n = 0; n < 4; ++n) acc[m][n] = zero;

  int rlo = lane & 15;
  int khi = lane >> 4;   // 0..3
  int wm = wave >> 1, wn = wave & 1;

  for (int k0 = 0; k0 < K; k0 += 64) {
    __syncthreads();   // previous-iteration reads done before overwrite
#pragma unroll
    for (int j = 0; j < 4; ++j) {
      gload16(gA0 + (size_t)j * 8 * ldkB + (size_t)k0 * 2, lA0 + j * 1024);
      gload16(gB0 + (size_t)j * 8 * ldkB + (size_t)k0 * 2, lB0 + j * 1024);
    }
    __syncthreads();   // compiler drains vmcnt before barrier
#pragma unroll
    for (int kk = 0; kk < 2; ++kk) {
      bf16x8 av[4], bv[4];
#pragma unroll
      for (int m = 0; m < 4; ++m) {
        int ra = wm * 64 + m * 16 + rlo;
        int pc = (kk * 4 + khi) ^ (ra & 7);
        av[m] = *reinterpret_cast<const bf16x8*>((const char*)la + ra * 128 + pc * 16);
      }
#pragma unroll
      for (int n = 0; n < 4; ++n) {
        int rb = wn * 64 + n * 16 + rlo;
        int pc = (kk * 4 + khi) ^ (rb & 7);
        bv[n] = *reinterpret_cast<const bf16x8*>((const char*)lb + rb * 128 + pc * 16);
      }
#pragma unroll
      for (int m = 0; m < 4; ++m)
#pragma unroll
        for (int n = 0; n < 4; ++n)
          acc[m][n] = __builtin_amdgcn_mfma_f32_16x16x32_bf16(av[m], bv[n], acc[m][n], 0, 0, 0);
    }
  }

  int obm = bm + wm * 64;
  int obn = bn + wn * 64;
  int crow = (lane >> 4) * 4;
  int ccol = lane & 15;
#pragma unroll
  for (int n = 0; n < 4; ++n) {
    int c = obn + n * 16 + ccol;
    float bc = (MODE == 2) ? 0.f : bias[c];
#pragma unroll
    for (int m = 0; m < 4; ++m) {
#pragma unroll
      for (int v = 0; v < 4; ++v) {
        int r = obm + m * 16 + crow + v;
        size_t idx = (size_t)r * N + c;
        float val = acc[m][n][v];
        if (MODE == 0) {
          float pvl = val + bc;
          out0[idx] = pvl;
          float e = pvl > 0.f ? pvl : expm1f(pvl);
          out1bf[idx] = (short)f2bf(e);
        } else if (MODE == 1) {
          float pvl = val + bc;
          out0[idx] = resid[idx] + 0.4f * (pvl > 0.f ? pvl : expm1f(pvl));
        } else {
          out0[idx] = val > 0.f ? val : 0.f;
        }
      }
    }
  }
}

extern "C" void kernel_launch(void* const* d_in, const int* in_sizes, int n_in,
                              void* d_out, int out_size, void* d_ws, size_t ws_size,
                              hipStream_t stream) {
  const float* x  = (const float*)d_in[0];
  const int* rows = (const int*)d_in[1];
  const int* cols = (const int*)d_in[2];
  const float* vals = (const float*)d_in[3];
  const float* W1 = (const float*)d_in[4];
  const float* b1 = (const float*)d_in[5];
  const float* W2 = (const float*)d_in[6];
  const float* b2 = (const float*)d_in[7];

  float* out_adj = (float*)d_out;
  float* out_hid = out_adj + (size_t)N_NODES * N_NODES;

  char* w = (char*)d_ws;
  size_t off = 0;
  auto alloc = [&](size_t bytes) -> void* {
    void* p = w + off;
    off += (bytes + 255) & ~(size_t)255;
    return p;
  };
  int* counts   = (int*)alloc(8192 * sizeof(int));
  int* offs     = (int*)alloc(8193 * sizeof(int));
  int* cursor   = (int*)alloc(8192 * sizeof(int));
  int* cols_s   = (int*)alloc((size_t)NEDGE * sizeof(int));
  float* vals_s = (float*)alloc((size_t)NEDGE * sizeof(float));
  float* b12    = (float*)alloc(HDIM * sizeof(float));
  short* Xbf    = (short*)alloc((size_t)N_NODES * HDIM * sizeof(short));   // x_bf, then x1_bf
  short* Tbf    = (short*)alloc((size_t)N_NODES * HDIM * sizeof(short));   // product gather src
  short* Abuf   = (short*)alloc((size_t)N_NODES * 1024 * sizeof(short));   // [Ax|Axx] bf16
  short* Bbuf   = (short*)alloc((size_t)512 * 1024 * sizeof(short));       // [W1|W2] bf16
  float* pre1   = (float*)alloc((size_t)N_NODES * HDIM * sizeof(float));
  float* Hf     = (float*)alloc((size_t)N_NODES * HDIM * sizeof(float));   // final x2 f32
  short* Hbuf   = (short*)alloc((size_t)N_NODES * HDIM * sizeof(short));   // normalized bf16

  // CSR build (sorted cols/vals, no eidx indirection)
  zero_kernel<<<32, 256, 0, stream>>>(counts);
  hist_kernel<<<NEDGE / 256, 256, 0, stream>>>(rows, counts);
  scan_kernel<<<1, 1024, 0, stream>>>(counts, offs, cursor);
  scatter_kernel<<<NEDGE / 256, 256, 0, stream>>>(rows, cols, vals, cursor, cols_s, vals_s);

  // weights / bias / x prep
  bias_kernel<<<2, 256, 0, stream>>>(b1, b2, b12);
  cast_kernel<<<(512 * 64) / 256, 256, 0, stream>>>(W1, Bbuf, 1024, 0);
  cast_kernel<<<(512 * 64) / 256, 256, 0, stream>>>(W2, Bbuf, 1024, 512);
  cast_kernel<<<2048, 256, 0, stream>>>(x, Xbf, 512, 0);

  // ---- layer 1 ----
  spmm_bf<0><<<2048, 256, 0, stream>>>(offs, cols_s, vals_s, Xbf, x, Abuf, Tbf);
  spmm_bf<2><<<2048, 256, 0, stream>>>(offs, cols_s, vals_s, Tbf, nullptr, Abuf + 512, nullptr);
  // pre1 = [Ax|Axx]@[W1|W2]^T + b12 ; x1_bf = bf16(elu(pre1)) -> Xbf (reuse)
  gemm_lds<0><<<256, 256, 0, stream>>>(Abuf, Bbuf, 512, 1024, 4, b12, nullptr, pre1, Xbf);

  // ---- layer 2 ----
  spmm_bf<1><<<2048, 256, 0, stream>>>(offs, cols_s, vals_s, Xbf, pre1, Abuf, Tbf);
  spmm_bf<2><<<2048, 256, 0, stream>>>(offs, cols_s, vals_s, Tbf, nullptr, Abuf + 512, nullptr);
  // x2 = pre1 + 0.4*elu([Ax2|Axx2]@[W1|W2]^T + b12) -> Hf
  gemm_lds<1><<<256, 256, 0, stream>>>(Abuf, Bbuf, 512, 1024, 4, b12, pre1, Hf, nullptr);

  // ---- decoder ----
  rownorm_kernel<<<2048, 256, 0, stream>>>(Hf, out_hid, Hbuf);
  gemm_lds<2><<<4096, 256, 0, stream>>>(Hbuf, Hbuf, 8192, 512, 64, nullptr, nullptr, out_adj, nullptr);
}